// Round 13
// baseline (323.518 us; speedup 1.0000x reference)
//
#include <hip/hip_runtime.h>
#include <hip/hip_bf16.h>
#include <math.h>

// LGCN layer, coarse-bucket counting sort + in-LDS sort + ASYNC gather reduce.
// R12 post-mortem: compiler pins VGPR at ~40 and never builds a deep load
//     pipeline (3 rounds of evidence) -> register-file MLP is a dead end.
// R13: use global_load_lds (cp.async analog): no VGPR dest, no wave block,
//     vmcnt-tracked. Per wave: issue 8 async feat-row fetches (256B each,
//     size=4 x 64 lanes) into LDS slots, one s_waitcnt vmcnt(0), consume 8.
//     Latency paid once per 8 edges/wave, overlapped across 16 waves/CU.
//     f16 table dropped (async granule is 4B/lane; absmax back to 2^-8).

#define D 64
#define SHIFT 5
#define NB (1 << SHIFT)          // dst nodes per bucket (32)
#define CMAX 2048                // max buckets (requires N <= 65536)
#define CHUNK 4096               // edges per block in scatter
#define CAP 2048                 // LDS edge capacity (bucket mean 1024)
#define GB 8                     // async gather batch per wave

__device__ __forceinline__ void async_row_load(const float* g, float* l) {
  // one 256B row: each lane fetches 4B from g+lane -> lds_base + lane*4
  __builtin_amdgcn_global_load_lds(
      (const __attribute__((address_space(1))) void*)g,
      (__attribute__((address_space(3))) void*)l, 4, 0, 0);
}

// ------- kernel 1: attention scalars + coarse hist ---------
__global__ __launch_bounds__(256) void precompute_att(
    const float* __restrict__ feat, const float* __restrict__ lin_w,
    const float* __restrict__ lin_b, const int* __restrict__ edst,
    float* __restrict__ s1, float* __restrict__ s2,
    int* __restrict__ ghist, int C, int N, int E) {
  __shared__ int h[CMAX];
  for (int i = threadIdx.x; i < C; i += 256) h[i] = 0;
  __syncthreads();

  const int E4 = E >> 2;
  const int4* edst4 = (const int4*)edst;
  for (int i4 = blockIdx.x * 256 + threadIdx.x; i4 < E4; i4 += gridDim.x * 256) {
    const int4 d = edst4[i4];
    atomicAdd(&h[d.x >> SHIFT], 1);
    atomicAdd(&h[d.y >> SHIFT], 1);
    atomicAdd(&h[d.z >> SHIFT], 1);
    atomicAdd(&h[d.w >> SHIFT], 1);
  }
  if (blockIdx.x == 0 && threadIdx.x == 0) {      // E%4 tail
    for (int e = E4 << 2; e < E; ++e) atomicAdd(&h[edst[e] >> SHIFT], 1);
  }

  const int lane = threadIdx.x & 63;
  const int wid  = (blockIdx.x * blockDim.x + threadIdx.x) >> 6;
  const int nw   = (gridDim.x * blockDim.x) >> 6;
  const float w1 = lin_w[lane];
  const float w2 = lin_w[64 + lane];
  const float b  = lin_b[0];
  for (int i = wid; i < N; i += nw) {
    const float f = feat[(size_t)i * D + lane];
    float v1 = f * w1;
    float v2 = f * w2;
    #pragma unroll
    for (int off = 32; off > 0; off >>= 1) {
      v1 += __shfl_down(v1, off, 64);
      v2 += __shfl_down(v2, off, 64);
    }
    if (lane == 0) {
      s1[i] = v1 + b;   // fold bias into s1
      s2[i] = v2;
    }
  }

  __syncthreads();
  for (int i = threadIdx.x; i < C; i += 256) {
    const int v = h[i];
    if (v) atomicAdd(&ghist[i], v);   // ghist pre-zeroed by memsetAsync
  }
}

// ------- kernel 2: exclusive scan of C<=2048 bucket counts (2 items/thread) --
__global__ __launch_bounds__(1024) void scan_coarse(
    const int* __restrict__ ghist, int* __restrict__ bstart,
    int* __restrict__ gcur, int C) {
  __shared__ int tot[1024];
  const int t = threadIdx.x;
  const int i0 = 2 * t, i1 = 2 * t + 1;
  const int v0 = (i0 < C) ? ghist[i0] : 0;
  const int v1 = (i1 < C) ? ghist[i1] : 0;
  const int s = v0 + v1;
  tot[t] = s;
  __syncthreads();
  for (int off = 1; off < 1024; off <<= 1) {
    int u = tot[t] + ((t >= off) ? tot[t - off] : 0);
    __syncthreads();
    tot[t] = u;
    __syncthreads();
  }
  const int excl = tot[t] - s;
  if (i0 < C) { bstart[i0] = excl;      gcur[i0] = excl; }
  if (i1 < C) { bstart[i1] = excl + v0; gcur[i1] = excl + v0; }
}

// ---------------- kernel 3: coarse scatter, LDS-staged runs ----------------
__global__ __launch_bounds__(256) void coarse_scatter(
    const int* __restrict__ esrc, const int* __restrict__ edst,
    const float* __restrict__ s1, const float* __restrict__ s2,
    int* __restrict__ gcur, uint2* __restrict__ ebuf, int E, int C) {
  __shared__ int h[CMAX];
  __shared__ int cur[CMAX];
  __shared__ int bl[CMAX];
  for (int i = threadIdx.x; i < C; i += 256) h[i] = 0;
  __syncthreads();
  const int E4 = E >> 2;
  const int4* edst4 = (const int4*)edst;
  const int4* esrc4 = (const int4*)esrc;
  const int b4 = blockIdx.x * (CHUNK >> 2);
  const bool tail0 = (blockIdx.x == 0) && (threadIdx.x == 0);

  #pragma unroll
  for (int k = 0; k < CHUNK / 1024; ++k) {
    const int i4 = b4 + threadIdx.x + 256 * k;
    if (i4 < E4) {
      const int4 d = edst4[i4];
      atomicAdd(&h[d.x >> SHIFT], 1);
      atomicAdd(&h[d.y >> SHIFT], 1);
      atomicAdd(&h[d.z >> SHIFT], 1);
      atomicAdd(&h[d.w >> SHIFT], 1);
    }
  }
  if (tail0) for (int e = E4 << 2; e < E; ++e) atomicAdd(&h[edst[e] >> SHIFT], 1);
  __syncthreads();
  for (int i = threadIdx.x; i < C; i += 256) {
    const int v = h[i];
    bl[i] = v ? atomicAdd(&gcur[i], v) : 0;
    cur[i] = 0;
  }
  __syncthreads();

  #pragma unroll
  for (int k = 0; k < CHUNK / 1024; ++k) {
    const int i4 = b4 + threadIdx.x + 256 * k;
    if (i4 < E4) {
      const int4 s = esrc4[i4];
      const int4 d = edst4[i4];
      const int ss[4] = {s.x, s.y, s.z, s.w};
      const int dd[4] = {d.x, d.y, d.z, d.w};
      float a1[4], a2[4];
      #pragma unroll
      for (int j = 0; j < 4; ++j) a1[j] = s1[ss[j]];   // independent gathers
      #pragma unroll
      for (int j = 0; j < 4; ++j) a2[j] = s2[dd[j]];
      #pragma unroll
      for (int j = 0; j < 4; ++j) {
        const float a = 1.0f / (1.0f + __expf(-fmaxf(a1[j] + a2[j], 0.0f)));
        const int bk = dd[j] >> SHIFT;
        const int r  = atomicAdd(&cur[bk], 1);
        ebuf[bl[bk] + r] =
            make_uint2((unsigned)ss[j] | ((unsigned)(dd[j] & (NB - 1)) << 26),
                       __float_as_uint(a));
      }
    }
  }
  if (tail0) {
    for (int e = E4 << 2; e < E; ++e) {
      const int sj = esrc[e], dj = edst[e];
      const float a = 1.0f / (1.0f + __expf(-fmaxf(s1[sj] + s2[dj], 0.0f)));
      const int bk = dj >> SHIFT;
      const int r  = atomicAdd(&cur[bk], 1);
      ebuf[bl[bk] + r] =
          make_uint2((unsigned)sj | ((unsigned)(dj & (NB - 1)) << 26),
                     __float_as_uint(a));
    }
  }
}

// ---------------- kernel 4: sort + async-gather reduce ----------------
// One block (256 thr, 4 waves) per bucket. Sort into sdata (chunk-local runs),
// then wave wv walks its contiguous slice in batches of GB: issue GB async
// row fetches -> slots, s_waitcnt vmcnt(0), consume GB (slot read + fmac,
// running acc flushed to sacc on wave-uniform node change).
__global__ __launch_bounds__(256, 4) void bucket_reduce(
    const float* __restrict__ feat, const float* __restrict__ norm,
    const int* __restrict__ bstart, const int* __restrict__ gcur,
    const uint2* __restrict__ ebuf, const float* __restrict__ W_rel,
    const float* __restrict__ loop_w, const float* __restrict__ evolve_w,
    float* __restrict__ out, int N) {
  __shared__ uint2 sdata[CAP];         // sorted entries, 16 KB
  __shared__ float slots[4 * GB * D];  // async landing pads, 8 KB
  __shared__ float sacc[NB * D];       // accumulator tile, 8 KB
  __shared__ int   hist[NB];
  __shared__ int   roff[NB];           // starts -> consumed into ends
  __shared__ int   degs[NB];

  const int tid  = threadIdx.x;
  const int lane = tid & 63;
  const int wv   = __builtin_amdgcn_readfirstlane(tid >> 6);   // 0..3
  const int b    = blockIdx.x;
  const int n0   = b << SHIFT;
  const int beg  = __builtin_amdgcn_readfirstlane(bstart[b]);
  const int end  = __builtin_amdgcn_readfirstlane(gcur[b]);    // bucket end

  float* myslots = &slots[wv * GB * D];

  for (int i = tid; i < NB * D; i += 256) sacc[i] = 0.0f;
  if (tid < NB) degs[tid] = 0;

  for (int cb = beg; cb < end; cb += CAP) {
    const int ccnt = min(CAP, end - cb);
    __syncthreads();                               // protect prev sdata/roff
    if (tid < NB) hist[tid] = 0;
    __syncthreads();
    // pass 1: histogram (coalesced global read of dl)
    for (int i = tid; i < ccnt; i += 256) {
      const unsigned x = ebuf[cb + i].x;
      atomicAdd(&hist[x >> 26], 1);
    }
    __syncthreads();
    // lanes 0..NB-1: shfl exclusive scan -> roff (starts); accumulate degs
    if (tid < NB) {
      const int v = hist[tid];
      degs[tid] += v;
      int incl = v;
      #pragma unroll
      for (int off = 1; off < NB; off <<= 1) {
        const int o = __shfl_up(incl, off, 64);
        if (tid >= off) incl += o;
      }
      roff[tid] = incl - v;
    }
    __syncthreads();
    // pass 2: rank atomic + sorted placement (roff becomes run ENDS)
    for (int i = tid; i < ccnt; i += 256) {
      const uint2 e = ebuf[cb + i];
      const int pos = atomicAdd(&roff[e.x >> 26], 1);
      sdata[pos] = e;
    }
    __syncthreads();

    // async-batched accumulate over this wave's contiguous slice
    const int j0   = wv * (NB / 4);
    const int wbeg = __builtin_amdgcn_readfirstlane(j0 == 0 ? 0 : roff[j0 - 1]);
    const int wend = __builtin_amdgcn_readfirstlane(roff[j0 + NB / 4 - 1]);

    int   cur = -1;
    float acc = 0.0f;
    int p = wbeg;
    while (p < wend) {
      const int g = min(GB, wend - p);     // wave-uniform
      int   dlr[GB];
      float atr[GB];
      #pragma unroll
      for (int q = 0; q < GB; ++q) {
        if (q < g) {
          const uint2 e = sdata[p + q];
          dlr[q] = (int)(e.x >> 26);
          atr[q] = __uint_as_float(e.y);
          async_row_load(feat + (size_t)(e.x & 0x03FFFFFFu) * D + lane,
                         myslots + q * D);
        }
      }
      __builtin_amdgcn_s_waitcnt(0x0F70);   // vmcnt(0): rows landed
      #pragma unroll
      for (int q = 0; q < GB; ++q) {
        if (q < g) {
          const float t = atr[q] * myslots[q * D + lane];
          if (dlr[q] != cur) {              // wave-uniform branch
            if (cur >= 0) sacc[cur * D + lane] += acc;
            cur = dlr[q];
            acc = t;
          } else {
            acc += t;
          }
        }
      }
      p += g;
    }
    if (cur >= 0) sacc[cur * D + lane] += acc;   // final flush
  }
  __syncthreads();

  // epilogue: matvecs + tanh for this wave's 8 nodes
  #pragma unroll
  for (int jj = 0; jj < NB / 4; ++jj) {
    const int j = wv * (NB / 4) + jj;
    const int n = n0 + j;
    if (n >= N) break;
    const float f  = feat[(size_t)n * D + lane];
    const float nr = norm[n];
    float nf, lm = 0.0f;
    if (degs[j] > 0) {
      const float pa = sacc[j * D + lane];
      float a1 = 0.0f;
      #pragma unroll 8
      for (int k = 0; k < D; ++k) {
        const float fb = __shfl(f, k, 64);
        const float pb = __shfl(pa, k, 64);
        a1 += pb * W_rel[k * D + lane];
        lm += fb * loop_w[k * D + lane];
      }
      nf = a1 * nr;
    } else {
      #pragma unroll 8
      for (int k = 0; k < D; ++k) {
        const float fb = __shfl(f, k, 64);
        lm += fb * evolve_w[k * D + lane];
      }
      nf = f * nr;   // zero in-degree keeps old feat
    }
    out[(size_t)n * D + lane] = tanhf(nf + lm);
  }
}

extern "C" void kernel_launch(void* const* d_in, const int* in_sizes, int n_in,
                              void* d_out, int out_size, void* d_ws, size_t ws_size,
                              hipStream_t stream) {
  const float* feat     = (const float*)d_in[0];
  const float* norm     = (const float*)d_in[1];
  const int*   esrc     = (const int*)d_in[2];
  const int*   edst     = (const int*)d_in[3];
  // d_in[4] = etype: no-op permutation per the reference
  const float* W_rel    = (const float*)d_in[5];
  const float* lin_w    = (const float*)d_in[6];
  const float* lin_b    = (const float*)d_in[7];
  const float* loop_w   = (const float*)d_in[8];
  const float* evolve_w = (const float*)d_in[9];
  float* out = (float*)d_out;

  const int N = in_sizes[1];   // norm is [N]   (N <= 65536: src fits 26 bits)
  const int E = in_sizes[2];   // edge_src is [E]
  const int C = (N + NB - 1) >> SHIFT;   // 1563 for N=50000

  // layout: s1[N] | s2[N] | bstart | gcur | ghist | ebuf[E]
  const size_t tab = (size_t)CMAX * sizeof(int);
  char* p = (char*)d_ws;
  float* s1     = (float*)p;                 p += (size_t)N * sizeof(float);
  float* s2     = (float*)p;                 p += (size_t)N * sizeof(float);
  int*   bstart = (int*)p;                   p += tab;
  int*   gcur   = (int*)p;                   p += tab;
  int*   ghist  = (int*)p;                   p += tab;
  uint2* ebuf   = (uint2*)p;

  const int eblocks = (E + CHUNK - 1) / CHUNK;   // 391 for E=1.6M

  hipMemsetAsync(ghist, 0, (size_t)C * sizeof(int), stream);
  precompute_att<<<512, 256, 0, stream>>>(feat, lin_w, lin_b, edst,
                                          s1, s2, ghist, C, N, E);
  scan_coarse<<<1, 1024, 0, stream>>>(ghist, bstart, gcur, C);
  coarse_scatter<<<eblocks, 256, 0, stream>>>(esrc, edst, s1, s2, gcur,
                                              ebuf, E, C);
  bucket_reduce<<<C, 256, 0, stream>>>(feat, norm, bstart, gcur, ebuf,
                                       W_rel, loop_w, evolve_w, out, N);
}

// Round 14
// 273.604 us; speedup vs baseline: 1.1824x; 1.1824x over previous
//
#include <hip/hip_runtime.h>
#include <hip/hip_bf16.h>
#include <hip/hip_fp16.h>
#include <math.h>

// LGCN layer. R13 post-mortem: async global_load_lds gather regressed (no
// cross-batch overlap, vmcnt(0) drain per 8 edges). R14 recombines the
// measured-best components:
//   - coarse scatter SHIFT 5 (R5/R9: no write amplification, ~60us)
//   - NEW fine_sort: per-bucket in-LDS counting sort, COALESCED writeback to
//     the same ebuf region + global fineoff[N+1] (fine CSR)
//   - R4-proven reducer: decoupled grid, wave-per-8-consecutive-nodes,
//     batched offsets via one vector load + readlane, unroll-16 walk of
//     global contiguous runs, no barriers -- 102us at f32; now f16 gather.

#define D 64
#define SHIFT 5
#define NB (1 << SHIFT)          // dst nodes per bucket (32)
#define CMAX 2048                // max buckets (requires N <= 65536)
#define CHUNK 4096               // edges per block in scatter
#define CAP 3072                 // LDS sort capacity (bucket mean 1024, max ~1.2K)
#define NPW 8                    // nodes per wave in reducer

// ------- kernel 1: attention scalars + f16 feat table + coarse hist ---------
__global__ __launch_bounds__(256) void precompute_att(
    const float* __restrict__ feat, const float* __restrict__ lin_w,
    const float* __restrict__ lin_b, const int* __restrict__ edst,
    float* __restrict__ s1, float* __restrict__ s2, __half* __restrict__ fh,
    int* __restrict__ ghist, int C, int N, int E) {
  __shared__ int h[CMAX];
  for (int i = threadIdx.x; i < C; i += 256) h[i] = 0;
  __syncthreads();

  const int E4 = E >> 2;
  const int4* edst4 = (const int4*)edst;
  for (int i4 = blockIdx.x * 256 + threadIdx.x; i4 < E4; i4 += gridDim.x * 256) {
    const int4 d = edst4[i4];
    atomicAdd(&h[d.x >> SHIFT], 1);
    atomicAdd(&h[d.y >> SHIFT], 1);
    atomicAdd(&h[d.z >> SHIFT], 1);
    atomicAdd(&h[d.w >> SHIFT], 1);
  }
  if (blockIdx.x == 0 && threadIdx.x == 0) {      // E%4 tail
    for (int e = E4 << 2; e < E; ++e) atomicAdd(&h[edst[e] >> SHIFT], 1);
  }

  const int lane = threadIdx.x & 63;
  const int wid  = (blockIdx.x * blockDim.x + threadIdx.x) >> 6;
  const int nw   = (gridDim.x * blockDim.x) >> 6;
  const float w1 = lin_w[lane];
  const float w2 = lin_w[64 + lane];
  const float b  = lin_b[0];
  for (int i = wid; i < N; i += nw) {
    const float f = feat[(size_t)i * D + lane];
    if (fh) fh[(size_t)i * D + lane] = __float2half(f);
    float v1 = f * w1;
    float v2 = f * w2;
    #pragma unroll
    for (int off = 32; off > 0; off >>= 1) {
      v1 += __shfl_down(v1, off, 64);
      v2 += __shfl_down(v2, off, 64);
    }
    if (lane == 0) {
      s1[i] = v1 + b;   // fold bias into s1
      s2[i] = v2;
    }
  }

  __syncthreads();
  for (int i = threadIdx.x; i < C; i += 256) {
    const int v = h[i];
    if (v) atomicAdd(&ghist[i], v);   // ghist pre-zeroed by memsetAsync
  }
}

// ------- kernel 2: exclusive scan of C<=2048 bucket counts (2 items/thread) --
__global__ __launch_bounds__(1024) void scan_coarse(
    const int* __restrict__ ghist, int* __restrict__ bstart,
    int* __restrict__ gcur, int C) {
  __shared__ int tot[1024];
  const int t = threadIdx.x;
  const int i0 = 2 * t, i1 = 2 * t + 1;
  const int v0 = (i0 < C) ? ghist[i0] : 0;
  const int v1 = (i1 < C) ? ghist[i1] : 0;
  const int s = v0 + v1;
  tot[t] = s;
  __syncthreads();
  for (int off = 1; off < 1024; off <<= 1) {
    int u = tot[t] + ((t >= off) ? tot[t - off] : 0);
    __syncthreads();
    tot[t] = u;
    __syncthreads();
  }
  const int excl = tot[t] - s;
  if (i0 < C) { bstart[i0] = excl;      gcur[i0] = excl; }
  if (i1 < C) { bstart[i1] = excl + v0; gcur[i1] = excl + v0; }
}

// ---------------- kernel 3: coarse scatter, LDS-staged runs ----------------
// Entry: x = src | dl<<26 (dl = dst & 31), y = att f32.
__global__ __launch_bounds__(256) void coarse_scatter(
    const int* __restrict__ esrc, const int* __restrict__ edst,
    const float* __restrict__ s1, const float* __restrict__ s2,
    int* __restrict__ gcur, uint2* __restrict__ ebuf, int E, int C) {
  __shared__ int h[CMAX];
  __shared__ int cur[CMAX];
  __shared__ int bl[CMAX];
  for (int i = threadIdx.x; i < C; i += 256) h[i] = 0;
  __syncthreads();
  const int E4 = E >> 2;
  const int4* edst4 = (const int4*)edst;
  const int4* esrc4 = (const int4*)esrc;
  const int b4 = blockIdx.x * (CHUNK >> 2);
  const bool tail0 = (blockIdx.x == 0) && (threadIdx.x == 0);

  #pragma unroll
  for (int k = 0; k < CHUNK / 1024; ++k) {
    const int i4 = b4 + threadIdx.x + 256 * k;
    if (i4 < E4) {
      const int4 d = edst4[i4];
      atomicAdd(&h[d.x >> SHIFT], 1);
      atomicAdd(&h[d.y >> SHIFT], 1);
      atomicAdd(&h[d.z >> SHIFT], 1);
      atomicAdd(&h[d.w >> SHIFT], 1);
    }
  }
  if (tail0) for (int e = E4 << 2; e < E; ++e) atomicAdd(&h[edst[e] >> SHIFT], 1);
  __syncthreads();
  for (int i = threadIdx.x; i < C; i += 256) {
    const int v = h[i];
    bl[i] = v ? atomicAdd(&gcur[i], v) : 0;
    cur[i] = 0;
  }
  __syncthreads();

  #pragma unroll
  for (int k = 0; k < CHUNK / 1024; ++k) {
    const int i4 = b4 + threadIdx.x + 256 * k;
    if (i4 < E4) {
      const int4 s = esrc4[i4];
      const int4 d = edst4[i4];
      const int ss[4] = {s.x, s.y, s.z, s.w};
      const int dd[4] = {d.x, d.y, d.z, d.w};
      float a1[4], a2[4];
      #pragma unroll
      for (int j = 0; j < 4; ++j) a1[j] = s1[ss[j]];   // independent gathers
      #pragma unroll
      for (int j = 0; j < 4; ++j) a2[j] = s2[dd[j]];
      #pragma unroll
      for (int j = 0; j < 4; ++j) {
        const float a = 1.0f / (1.0f + __expf(-fmaxf(a1[j] + a2[j], 0.0f)));
        const int bk = dd[j] >> SHIFT;
        const int r  = atomicAdd(&cur[bk], 1);
        ebuf[bl[bk] + r] =
            make_uint2((unsigned)ss[j] | ((unsigned)(dd[j] & (NB - 1)) << 26),
                       __float_as_uint(a));
      }
    }
  }
  if (tail0) {
    for (int e = E4 << 2; e < E; ++e) {
      const int sj = esrc[e], dj = edst[e];
      const float a = 1.0f / (1.0f + __expf(-fmaxf(s1[sj] + s2[dj], 0.0f)));
      const int bk = dj >> SHIFT;
      const int r  = atomicAdd(&cur[bk], 1);
      ebuf[bl[bk] + r] =
          make_uint2((unsigned)sj | ((unsigned)(dj & (NB - 1)) << 26),
                     __float_as_uint(a));
    }
  }
}

// ---------------- kernel 4: per-bucket fine sort + fineoff ----------------
// One block per coarse bucket: in-LDS counting sort by dl, coalesced writeback
// to the SAME ebuf region, per-node absolute starts -> fineoff[N+1].
__global__ __launch_bounds__(256) void fine_sort(
    int* __restrict__ fineoff, const int* __restrict__ bstart,
    const int* __restrict__ gcur, uint2* __restrict__ ebuf, int C, int N, int E) {
  __shared__ uint2 sdata[CAP];    // 24 KB
  __shared__ int   hist[NB];
  __shared__ int   roff[NB];      // starts -> consumed into ends by place pass

  const int tid = threadIdx.x;
  const int b   = blockIdx.x;
  const int n0  = b << SHIFT;
  const int beg = __builtin_amdgcn_readfirstlane(bstart[b]);
  const int end = __builtin_amdgcn_readfirstlane(gcur[b]);
  const int cnt = min(end - beg, CAP);

  if (tid < NB) hist[tid] = 0;
  __syncthreads();
  for (int i = tid; i < cnt; i += 256) {
    atomicAdd(&hist[ebuf[beg + i].x >> 26], 1);
  }
  __syncthreads();
  if (tid < NB) {
    const int v = hist[tid];
    int incl = v;
    #pragma unroll
    for (int off = 1; off < NB; off <<= 1) {
      const int o = __shfl_up(incl, off, 64);
      if (tid >= off) incl += o;
    }
    const int start = incl - v;
    roff[tid] = start;
    const int n = n0 + tid;
    if (n < N) fineoff[n] = beg + start;        // absolute run start
    if (b == C - 1 && tid == 0) fineoff[N] = E; // sentinel
  }
  __syncthreads();
  for (int i = tid; i < cnt; i += 256) {        // sorted placement
    const uint2 e = ebuf[beg + i];
    const int pos = atomicAdd(&roff[e.x >> 26], 1);
    sdata[pos] = e;
  }
  __syncthreads();
  for (int i = tid; i < cnt; i += 256) {        // coalesced writeback
    ebuf[beg + i] = sdata[i];
  }
}

// ---------------- kernel 5: R4-style fine-CSR reduce + finalize -------------
// Wave handles NPW consecutive nodes; NPW+1 bounds in one vector load +
// readlane; unroll-16 walk of the node's contiguous global run; f16 gather.
template <bool USEH>
__global__ __launch_bounds__(256) void reduce_finalize(
    const float* __restrict__ feat, const __half* __restrict__ fh,
    const float* __restrict__ norm, const int* __restrict__ fineoff,
    const uint2* __restrict__ ebuf, const float* __restrict__ W_rel,
    const float* __restrict__ loop_w, const float* __restrict__ evolve_w,
    float* __restrict__ out, int N) {
  const int lane = threadIdx.x & 63;
  const int wid  = blockIdx.x * 4 + (threadIdx.x >> 6);
  const int n0   = wid * NPW;
  if (n0 >= N) return;
  const int jmax = min(NPW, N - n0);

  // lane i in [0, NPW] holds fineoff[n0+i]
  int off_v = 0;
  if (lane <= NPW && n0 + lane <= N) off_v = fineoff[n0 + lane];

  for (int j = 0; j < jmax; ++j) {
    const int n   = n0 + j;
    const int beg = __builtin_amdgcn_readlane(off_v, j);
    const int end = __builtin_amdgcn_readlane(off_v, j + 1);
    const float f  = feat[(size_t)n * D + lane];
    const float nr = norm[n];

    float agg = 0.0f;
    int p = beg;
    for (; p + 16 <= end; p += 16) {   // 16 independent gathers in flight
      uint2 ee[16];
      #pragma unroll
      for (int q = 0; q < 16; ++q) ee[q] = ebuf[p + q];
      float ff[16];
      #pragma unroll
      for (int q = 0; q < 16; ++q) {
        const size_t ix = (size_t)(ee[q].x & 0x03FFFFFFu) * D + lane;
        ff[q] = USEH ? __half2float(fh[ix]) : feat[ix];
      }
      #pragma unroll
      for (int q = 0; q < 16; ++q) agg += __uint_as_float(ee[q].y) * ff[q];
    }
    for (; p + 4 <= end; p += 4) {
      uint2 ee[4];
      #pragma unroll
      for (int q = 0; q < 4; ++q) ee[q] = ebuf[p + q];
      #pragma unroll
      for (int q = 0; q < 4; ++q) {
        const size_t ix = (size_t)(ee[q].x & 0x03FFFFFFu) * D + lane;
        agg += __uint_as_float(ee[q].y) * (USEH ? __half2float(fh[ix]) : feat[ix]);
      }
    }
    for (; p < end; ++p) {
      const uint2 en = ebuf[p];
      const size_t ix = (size_t)(en.x & 0x03FFFFFFu) * D + lane;
      agg += __uint_as_float(en.y) * (USEH ? __half2float(fh[ix]) : feat[ix]);
    }

    const bool hm = end > beg;   // wave-uniform branch
    float nf, lm = 0.0f;
    if (hm) {
      float a1 = 0.0f;
      #pragma unroll 8
      for (int k = 0; k < D; ++k) {
        const float fb = __shfl(f, k, 64);
        const float pb = __shfl(agg, k, 64);
        a1 += pb * W_rel[k * D + lane];
        lm += fb * loop_w[k * D + lane];
      }
      nf = a1 * nr;
    } else {
      #pragma unroll 8
      for (int k = 0; k < D; ++k) {
        const float fb = __shfl(f, k, 64);
        lm += fb * evolve_w[k * D + lane];
      }
      nf = f * nr;   // zero in-degree keeps old feat
    }
    out[(size_t)n * D + lane] = tanhf(nf + lm);
  }
}

extern "C" void kernel_launch(void* const* d_in, const int* in_sizes, int n_in,
                              void* d_out, int out_size, void* d_ws, size_t ws_size,
                              hipStream_t stream) {
  const float* feat     = (const float*)d_in[0];
  const float* norm     = (const float*)d_in[1];
  const int*   esrc     = (const int*)d_in[2];
  const int*   edst     = (const int*)d_in[3];
  // d_in[4] = etype: no-op permutation per the reference
  const float* W_rel    = (const float*)d_in[5];
  const float* lin_w    = (const float*)d_in[6];
  const float* lin_b    = (const float*)d_in[7];
  const float* loop_w   = (const float*)d_in[8];
  const float* evolve_w = (const float*)d_in[9];
  float* out = (float*)d_out;

  const int N = in_sizes[1];   // norm is [N]   (N <= 65536: src fits 26 bits)
  const int E = in_sizes[2];   // edge_src is [E]
  const int C = (N + NB - 1) >> SHIFT;   // 1563 for N=50000

  // layout: s1|s2 | fineoff[N+1] | bstart|gcur|ghist | fh (optional) | ebuf[E]
  const size_t tab      = (size_t)CMAX * sizeof(int);
  const size_t fh_bytes = (size_t)N * D * sizeof(__half);
  const size_t fixed    = (size_t)N * 2 * sizeof(float) +
                          (size_t)(N + 1) * sizeof(int) + 3 * tab +
                          (size_t)E * sizeof(uint2);
  const bool use_h = ws_size >= fixed + fh_bytes;

  char* p = (char*)d_ws;
  float*  s1      = (float*)p;        p += (size_t)N * sizeof(float);
  float*  s2      = (float*)p;        p += (size_t)N * sizeof(float);
  int*    fineoff = (int*)p;          p += (size_t)(N + 1) * sizeof(int);
  int*    bstart  = (int*)p;          p += tab;
  int*    gcur    = (int*)p;          p += tab;
  int*    ghist   = (int*)p;          p += tab;
  __half* fh      = nullptr;
  if (use_h) { fh = (__half*)p;       p += fh_bytes; }
  uint2*  ebuf    = (uint2*)p;

  const int eblocks = (E + CHUNK - 1) / CHUNK;     // 391 for E=1.6M
  const int rblocks = (N + NPW * 4 - 1) / (NPW * 4);   // 1563 for N=50000

  hipMemsetAsync(ghist, 0, (size_t)C * sizeof(int), stream);
  precompute_att<<<512, 256, 0, stream>>>(feat, lin_w, lin_b, edst,
                                          s1, s2, fh, ghist, C, N, E);
  scan_coarse<<<1, 1024, 0, stream>>>(ghist, bstart, gcur, C);
  coarse_scatter<<<eblocks, 256, 0, stream>>>(esrc, edst, s1, s2, gcur,
                                              ebuf, E, C);
  fine_sort<<<C, 256, 0, stream>>>(fineoff, bstart, gcur, ebuf, C, N, E);
  if (use_h) {
    reduce_finalize<true><<<rblocks, 256, 0, stream>>>(
        feat, fh, norm, fineoff, ebuf, W_rel, loop_w, evolve_w, out, N);
  } else {
    reduce_finalize<false><<<rblocks, 256, 0, stream>>>(
        feat, fh, norm, fineoff, ebuf, W_rel, loop_w, evolve_w, out, N);
  }
}